// Round 13
// baseline (771.497 us; speedup 1.0000x reference)
//
#include <hip/hip_runtime.h>
#include <cstdint>

#define EPSF 1e-5f

namespace {

typedef _Float16 f16;
typedef _Float16 v8h __attribute__((ext_vector_type(8)));
typedef float v4f __attribute__((ext_vector_type(4)));

constexpr int B  = 32;
constexpr int T0 = 2048, F0 = 20;
constexpr int T1 = 2044, T2 = 2040, T3 = 2034;
constexpr int TS = 2048;   // uniform stored t-rows per (b, channel-octet)

// async global->LDS DMA, 16B per lane; LDS dest = wave-uniform base + lane*16
__device__ __forceinline__ void gload16(const void* g, void* l) {
    typedef const __attribute__((address_space(1))) void* gp_t;
    typedef __attribute__((address_space(3))) void* lp_t;
    __builtin_amdgcn_global_load_lds((gp_t)(unsigned long long)g,
                                     (lp_t)(unsigned int)(unsigned long long)l,
                                     16, 0, 0);
}
__device__ __forceinline__ void wait_vm4() { asm volatile("s_waitcnt vmcnt(4)" ::: "memory"); }
__device__ __forceinline__ void wait_vm0() { asm volatile("s_waitcnt vmcnt(0)" ::: "memory"); }

// x [B, T0, F0] fp32 -> xT [b][3 oct][TS][8] fp16; blocks 0..15 also zero st[4096]
__global__ __launch_bounds__(256) void transpose_x(const float* __restrict__ x,
                                                   f16* __restrict__ xT,
                                                   float* __restrict__ stZ)
{
    int idx = blockIdx.x * 256 + threadIdx.x;
    if (idx < 4096) stZ[idx] = 0.f;            // zero st1..st4 (atomic stats targets)
    constexpr int total = B * 3 * TS * 8;
    if (idx >= total) return;
    int fl = idx & 7;
    int t  = (idx >> 3) & (TS - 1);
    int fo = (idx >> 14) % 3;
    int b  = idx / (3 << 14);
    int f  = fo * 8 + fl;
    float v = (f < F0) ? x[((size_t)b * T0 + t) * F0 + f] : 0.f;
    xT[idx] = (f16)v;
}

// Fold prev-layer BN into weights, cast fp16, reorder K c-major (k = c*Fp + f),
// and write SWIZZLED slab order: [o/128][k/8][o%128][8] (1KB-contiguous DMA slabs).
__global__ __launch_bounds__(256) void fold_mfma(
    const float* __restrict__ W, const float* __restrict__ bias,
    const float* __restrict__ st, const float* __restrict__ gamma, const float* __restrict__ beta,
    f16* __restrict__ Wh, float* __restrict__ bf,
    int Oreal, int Freal, int Fp, int C, int Cin, int CinOrig, float invN)
{
    int o = blockIdx.x;
    auto sidx = [&](int k) {
        return ((size_t)((o >> 7) * (Cin >> 3) + (k >> 3)) * 128 + (o & 127)) * 8 + (k & 7);
    };
    if (o >= Oreal) {
        for (int k = threadIdx.x; k < Cin; k += 256) Wh[sidx(k)] = (f16)0.f;
        if (threadIdx.x == 0) bf[o] = 0.f;
        return;
    }
    float local = 0.f;
    for (int k = threadIdx.x; k < Cin; k += 256) {
        int c = k / Fp, f = k - c * Fp;
        float wv = 0.f;
        if (c < C && f < Freal) {
            float sc = 1.f, sh = 0.f;
            if (st) {
                float mean = st[f] * invN;
                float var  = st[Freal + f] * invN - mean * mean;
                sc = rsqrtf(var + EPSF);
                if (gamma) sc *= gamma[f];
                sh = (beta ? beta[f] : 0.f) - mean * sc;
            }
            float w = W[(size_t)o * CinOrig + f * C + c];
            wv = w * sc;
            local += w * sh;
        }
        Wh[sidx(k)] = (f16)wv;
    }
#pragma unroll
    for (int d = 32; d; d >>= 1) local += __shfl_down(local, d);
    __shared__ float red[4];
    if ((threadIdx.x & 63) == 0) red[threadIdx.x >> 6] = local;
    __syncthreads();
    if (threadIdx.x == 0) bf[o] = bias[o] + red[0] + red[1] + red[2] + red[3];
}

// Fused splice+conv via MFMA; 1KB-coalesced DMA staging, dbuf pipeline (vmcnt(4)).
// Per-channel stats accumulated via device-scope atomics into st[o], st[512+o].
template<int ACT, int FPR, int CIN>
__global__ __launch_bounds__(256, 4) void conv_mfma(
    const f16* __restrict__ inT, const f16* __restrict__ Wh,
    const float* __restrict__ bias, f16* __restrict__ outT,
    float* __restrict__ st, int O, int Tout, int offMul)
{
    __shared__ __align__(16) f16 Ilds[2][4 * 128 * 8];
    __shared__ __align__(16) f16 Wlds[2][4 * 128 * 8];
    __shared__ float redS[2][128];
    __shared__ float redQ[2][128];
    const int tid  = threadIdx.x;
    const int lane = tid & 63, wave = tid >> 6;
    const int wt = wave & 1, wo = wave >> 1;
    const int quad = lane >> 4, l16 = lane & 15;
    const int tB = blockIdx.x * 128, oB = blockIdx.y * 128, b = blockIdx.z;
    const f16* inb = inT + (size_t)b * FPR * TS;          // [c_oct][TS][8]
    const size_t wBase = (size_t)(oB >> 7) * (CIN >> 3);

    auto stage = [&](int iB, int pb) {
#pragma unroll
        for (int j = 0; j < 4; ++j) {
            int s = wave * 4 + j;
            int koct = (s & 7) >> 1, half = s & 1;
            if (s < 8) {
                int kidx = iB + koct * 8;
                int c = kidx / FPR, f = kidx - c * FPR;
                int t = tB + half * 64 + lane + c * offMul;
                gload16(inb + ((size_t)(f >> 3) * TS + t) * 8,
                        &Ilds[pb][(koct * 128 + half * 64) * 8]);
            } else {
                gload16(Wh + ((wBase + (iB >> 3) + koct) * 128 + half * 64 + lane) * 8,
                        &Wlds[pb][(koct * 128 + half * 64) * 8]);
            }
        }
    };

    v4f acc[4][4];
#pragma unroll
    for (int mi = 0; mi < 4; ++mi)
#pragma unroll
        for (int ni = 0; ni < 4; ++ni)
#pragma unroll
            for (int r = 0; r < 4; ++r) acc[mi][ni][r] = 0.f;

    constexpr int nIter = CIN >> 5;
    stage(0, 0);
#pragma unroll 2
    for (int k = 0; k < nIter; ++k) {
        const int pb = k & 1;
        __syncthreads();                        // readers of pb^1 done
        if (k + 1 < nIter) { stage((k + 1) * 32, pb ^ 1); wait_vm4(); }
        else               { wait_vm0(); }
        __syncthreads();                        // stage(k) complete everywhere
        v8h afr[4], bfr[4];
#pragma unroll
        for (int mi = 0; mi < 4; ++mi)
            afr[mi] = *(const v8h*)&Ilds[pb][(quad * 128 + wt * 64 + mi * 16 + l16) * 8];
#pragma unroll
        for (int ni = 0; ni < 4; ++ni)
            bfr[ni] = *(const v8h*)&Wlds[pb][(quad * 128 + wo * 64 + ni * 16 + l16) * 8];
#pragma unroll
        for (int mi = 0; mi < 4; ++mi)
#pragma unroll
            for (int ni = 0; ni < 4; ++ni)
                acc[mi][ni] = __builtin_amdgcn_mfma_f32_16x16x32_f16(
                    afr[mi], bfr[ni], acc[mi][ni], 0, 0, 0);
    }

    float Sl[4] = {0, 0, 0, 0}, Ql[4] = {0, 0, 0, 0};
#pragma unroll
    for (int ni = 0; ni < 4; ++ni) {
        const int o  = oB + wo * 64 + ni * 16 + l16;
        const float bs = bias[o];
        f16* orow = outT + (size_t)b * O * TS + (size_t)(o >> 3) * TS * 8 + (o & 7);
#pragma unroll
        for (int mi = 0; mi < 4; ++mi)
#pragma unroll
            for (int r = 0; r < 4; ++r) {
                int t = tB + wt * 64 + mi * 16 + quad * 4 + r;
                if (t < Tout) {
                    float v = acc[mi][ni][r] + bs;
                    v = fmaxf(v, 0.f);
                    if (ACT == 2) v = fminf(v, 6.f);
                    orow[(size_t)t * 8] = (f16)v;
                    Sl[ni] += v; Ql[ni] += v * v;
                }
            }
    }
#pragma unroll
    for (int ni = 0; ni < 4; ++ni) {
        float s = Sl[ni], q = Ql[ni];
        s += __shfl_down(s, 32); q += __shfl_down(q, 32);
        s += __shfl_down(s, 16); q += __shfl_down(q, 16);
        if (lane < 16) {
            redS[wt][wo * 64 + ni * 16 + lane] = s;
            redQ[wt][wo * 64 + ni * 16 + lane] = q;
        }
    }
    __syncthreads();
    if (tid < 128) {
        atomicAdd(&st[oB + tid],       redS[0][tid] + redS[1][tid]);
        atomicAdd(&st[512 + oB + tid], redQ[0][tid] + redQ[1][tid]);
    }
}

// L5: MFMA conv 1536x512 + relu6 + per-(b,o) sum/sumsq over a 256-t chunk.
// Grid 3072 (even 3 rounds of 4/CU). Swizzle: chunk cz pinned to XCD (L%8),
// all 12 oB blocks of a chunk on the same XCD.
template<int CIN>
__global__ __launch_bounds__(256, 4) void pool_mfma(
    const f16* __restrict__ inT, const f16* __restrict__ Wh,
    const float* __restrict__ bias, float* __restrict__ Sp, float* __restrict__ Qp,
    int T, int Opad)
{
    const int L    = blockIdx.x;
    const int slot = L >> 3;                       // 0..383
    const int oB   = (slot % 12) * 128;
    const int cz   = (L & 7) + 8 * (slot / 12);    // 0..255
    const int b    = cz & 31, z = cz >> 5;         // z: 0..7

    __shared__ __align__(16) f16 Ilds[2][4 * 128 * 8];
    __shared__ __align__(16) f16 Wlds[2][4 * 128 * 8];
    __shared__ float redS[2][128];
    __shared__ float redQ[2][128];
    const int tid  = threadIdx.x;
    const int lane = tid & 63, wave = tid >> 6;
    const int wt = wave & 1, wo = wave >> 1;
    const int quad = lane >> 4, l16 = lane & 15;
    const f16* inb = inT + (size_t)b * CIN * TS;
    const size_t wBase = (size_t)(oB >> 7) * (CIN >> 3);

    auto stage = [&](int t0, int iB, int pb) {
#pragma unroll
        for (int j = 0; j < 4; ++j) {
            int s = wave * 4 + j;
            int koct = (s & 7) >> 1, half = s & 1;
            if (s < 8) {
                gload16(inb + ((size_t)((iB >> 3) + koct) * TS + t0 + half * 64 + lane) * 8,
                        &Ilds[pb][(koct * 128 + half * 64) * 8]);
            } else {
                gload16(Wh + ((wBase + (iB >> 3) + koct) * 128 + half * 64 + lane) * 8,
                        &Wlds[pb][(koct * 128 + half * 64) * 8]);
            }
        }
    };

    float Sl[4] = {0, 0, 0, 0}, Ql[4] = {0, 0, 0, 0};
    float bs[4];
#pragma unroll
    for (int ni = 0; ni < 4; ++ni) bs[ni] = bias[oB + wo * 64 + ni * 16 + l16];

    const int tBase = z * 256;
    constexpr int kPer  = CIN >> 5;             // 16
    constexpr int total = 2 * kPer;             // 2 chunks of 128 t per block

    v4f acc[4][4];
#pragma unroll
    for (int mi = 0; mi < 4; ++mi)
#pragma unroll
        for (int ni = 0; ni < 4; ++ni)
#pragma unroll
            for (int r = 0; r < 4; ++r) acc[mi][ni][r] = 0.f;

    stage(tBase, 0, 0);
#pragma unroll 2
    for (int it = 0; it < total; ++it) {
        const int pb = it & 1;
        __syncthreads();
        if (it + 1 < total) {
            int nx = it + 1;
            stage(tBase + (nx >> 4) * 128, (nx & (kPer - 1)) * 32, pb ^ 1);
            wait_vm4();
        } else {
            wait_vm0();
        }
        __syncthreads();
        v8h afr[4], bfr[4];
#pragma unroll
        for (int mi = 0; mi < 4; ++mi)
            afr[mi] = *(const v8h*)&Ilds[pb][(quad * 128 + wt * 64 + mi * 16 + l16) * 8];
#pragma unroll
        for (int ni = 0; ni < 4; ++ni)
            bfr[ni] = *(const v8h*)&Wlds[pb][(quad * 128 + wo * 64 + ni * 16 + l16) * 8];
#pragma unroll
        for (int mi = 0; mi < 4; ++mi)
#pragma unroll
            for (int ni = 0; ni < 4; ++ni)
                acc[mi][ni] = __builtin_amdgcn_mfma_f32_16x16x32_f16(
                    afr[mi], bfr[ni], acc[mi][ni], 0, 0, 0);

        if ((it & (kPer - 1)) == kPer - 1) {    // chunk done: flush acc -> Sl/Ql
            int tB = tBase + (it >> 4) * 128;
#pragma unroll
            for (int ni = 0; ni < 4; ++ni)
#pragma unroll
                for (int mi = 0; mi < 4; ++mi)
#pragma unroll
                    for (int r = 0; r < 4; ++r) {
                        int t = tB + wt * 64 + mi * 16 + quad * 4 + r;
                        if (t < T) {
                            float v = fminf(fmaxf(acc[mi][ni][r] + bs[ni], 0.f), 6.f);
                            Sl[ni] += v; Ql[ni] += v * v;
                        }
                        acc[mi][ni][r] = 0.f;
                    }
        }
    }

#pragma unroll
    for (int ni = 0; ni < 4; ++ni) {
        float s = Sl[ni], q = Ql[ni];
        s += __shfl_down(s, 32); q += __shfl_down(q, 32);
        s += __shfl_down(s, 16); q += __shfl_down(q, 16);
        if (lane < 16) {
            redS[wt][wo * 64 + ni * 16 + lane] = s;
            redQ[wt][wo * 64 + ni * 16 + lane] = q;
        }
    }
    __syncthreads();
    if (tid < 128) {
        int o = oB + tid;
        Sp[((size_t)z * B + b) * Opad + o] = redS[0][tid] + redS[1][tid];
        Qp[((size_t)z * B + b) * Opad + o] = redQ[0][tid] + redQ[1][tid];
    }
}

// bn5 (global over B,T) + per-(b,c) mean/std(ddof=1) -> stat [B, 2*Oreal]
__global__ __launch_bounds__(256) void pool_finalize(
    const float* __restrict__ Sp, const float* __restrict__ Qp,
    const float* __restrict__ g5, const float* __restrict__ b5,
    float* __restrict__ stat, int Opad, int Oreal, int T)
{
    int co = blockIdx.x * 256 + threadIdx.x;
    if (co >= Oreal) return;
    double sS = 0, sQ = 0;
    for (int z = 0; z < 8; ++z)
        for (int b = 0; b < B; ++b) {
            sS += Sp[((size_t)z * B + b) * Opad + co];
            sQ += Qp[((size_t)z * B + b) * Opad + co];
        }
    double invN = 1.0 / ((double)B * T);
    double m = sS * invN;
    double v = sQ * invN - m * m;
    float sc = g5[co] * rsqrtf((float)v + EPSF);
    float sh = b5[co] - (float)m * sc;
    for (int b = 0; b < B; ++b) {
        double sb = 0, qb = 0;
        for (int z = 0; z < 8; ++z) {
            sb += Sp[((size_t)z * B + b) * Opad + co];
            qb += Qp[((size_t)z * B + b) * Opad + co];
        }
        double mb = sb / T;
        double vb = (qb - sb * sb / T) / (T - 1);
        if (vb < 0) vb = 0;
        stat[(size_t)b * 2 * Oreal + co]         = (float)mb * sc + sh;
        stat[(size_t)b * 2 * Oreal + Oreal + co] = sqrtf((float)vb) * fabsf(sc);
    }
}

// Fused FC + batch-BN: block per output channel o. Computes
// y[b] = relu6(dot(x[b,:],W[o,:])+bias[o]) for all b, then BN over b, writes out[b*O+o].
__global__ __launch_bounds__(256) void fc_bn(const float* __restrict__ x,
                                             const float* __restrict__ W,
                                             const float* __restrict__ bias,
                                             const float* __restrict__ g,
                                             const float* __restrict__ be,
                                             float* __restrict__ out, int Cin, int O)
{
    const int o = blockIdx.x;
    const int lane = threadIdx.x & 63, wv = threadIdx.x >> 6;
    __shared__ float yb[B];
    const float* wr = W + (size_t)o * Cin;
    for (int b = wv; b < B; b += 4) {
        const float* xr = x + (size_t)b * Cin;
        float s = 0.f;
        for (int c = lane; c < Cin; c += 64) s = fmaf(xr[c], wr[c], s);
#pragma unroll
        for (int d = 32; d; d >>= 1) s += __shfl_down(s, d);
        if (lane == 0) yb[b] = fminf(fmaxf(s + bias[o], 0.f), 6.f);
    }
    __syncthreads();
    if (threadIdx.x < 64) {
        float v = (lane < B) ? yb[lane] : 0.f;
        float s = v, q = v * v;
#pragma unroll
        for (int d = 16; d; d >>= 1) { s += __shfl_down(s, d); q += __shfl_down(q, d); }
        s = __shfl(s, 0); q = __shfl(q, 0);
        float m  = s / B;
        float var = q / B - m * m;
        float sc = g[o] * rsqrtf(var + EPSF);
        float sh = be[o] - m * sc;
        if (lane < B) out[(size_t)lane * O + o] = yb[lane] * sc + sh;
    }
}

} // anonymous namespace

extern "C" void kernel_launch(void* const* d_in, const int* in_sizes, int n_in,
                              void* d_out, int out_size, void* d_ws, size_t ws_size,
                              hipStream_t stream)
{
    (void)in_sizes; (void)n_in; (void)out_size; (void)ws_size;
    const float* x     = (const float*)d_in[0];
    const float* h1_w  = (const float*)d_in[1];
    const float* h1_b  = (const float*)d_in[2];
    const float* h2_w  = (const float*)d_in[3];
    const float* h2_b  = (const float*)d_in[4];
    const float* bn2_g = (const float*)d_in[5];
    const float* bn2_b = (const float*)d_in[6];
    const float* h3_w  = (const float*)d_in[7];
    const float* h3_b  = (const float*)d_in[8];
    const float* bn3_g = (const float*)d_in[9];
    const float* bn3_b = (const float*)d_in[10];
    const float* h4_w  = (const float*)d_in[11];
    const float* h4_b  = (const float*)d_in[12];
    const float* bn4_g = (const float*)d_in[13];
    const float* bn4_b = (const float*)d_in[14];
    const float* h5_w  = (const float*)d_in[15];
    const float* h5_b  = (const float*)d_in[16];
    const float* bn5_g = (const float*)d_in[17];
    const float* bn5_b = (const float*)d_in[18];
    const float* l1_w  = (const float*)d_in[19];
    const float* l1_b  = (const float*)d_in[20];
    const float* bn6_g = (const float*)d_in[21];
    const float* bn6_b = (const float*)d_in[22];
    const float* l2_w  = (const float*)d_in[23];
    const float* l2_b  = (const float*)d_in[24];
    const float* bn7_g = (const float*)d_in[25];
    const float* bn7_b = (const float*)d_in[26];

    char* ws = (char*)d_ws;
    size_t off = 0;
    auto alloc = [&](size_t bytes) {
        char* p = ws + off;
        off += (bytes + 255) & ~(size_t)255;
        return (void*)p;
    };
    f16* xT    = (f16*)alloc(((size_t)B * 3  * TS * 8 + 2048) * 2);
    f16* bufA  = (f16*)alloc(((size_t)B * 64 * TS * 8 + 2048) * 2);  // o1, later o3
    f16* bufB  = (f16*)alloc(((size_t)B * 64 * TS * 8 + 2048) * 2);  // o2, later o4
    f16* Wh1   = (f16*)alloc((size_t)512 * 128 * 2);
    f16* Wh2   = (f16*)alloc((size_t)512 * 1536 * 2);
    f16* Wh3   = (f16*)alloc((size_t)512 * 1536 * 2);
    f16* Wh4   = (f16*)alloc((size_t)512 * 512 * 2);
    f16* Wh5   = (f16*)alloc((size_t)1536 * 512 * 2);
    float* bf1 = (float*)alloc(512 * 4);
    float* bf2 = (float*)alloc(512 * 4);
    float* bf3 = (float*)alloc(512 * 4);
    float* bf4 = (float*)alloc(512 * 4);
    float* bf5 = (float*)alloc(1536 * 4);
    float* stZ = (float*)alloc(4096 * 4);       // st1..st4, zeroed by transpose_x
    float* st1 = stZ, *st2 = stZ + 1024, *st3 = stZ + 2048, *st4 = stZ + 3072;
    float* Sp  = (float*)alloc((size_t)8 * B * 1536 * 4);
    float* Qp  = (float*)alloc((size_t)8 * B * 1536 * 4);
    float* stat = (float*)alloc((size_t)B * 3000 * 4);
    float* f1  = (float*)alloc((size_t)B * 512 * 4);

    transpose_x<<<(B * 3 * TS * 8 + 255) / 256, 256, 0, stream>>>(x, xT, stZ);

    // L1: reorder/cast/swizzle W1 (no prev BN); splice(0..4), Cin pad->128
    fold_mfma<<<512, 256, 0, stream>>>(h1_w, h1_b, nullptr, nullptr, nullptr,
                                       Wh1, bf1, 512, 20, 24, 5, 128, 100, 0.f);
    conv_mfma<1, 24, 128><<<dim3(16, 4, B), 256, 0, stream>>>(
        xT, Wh1, bf1, bufA, st1, 512, T1, 1);

    // L2: fold bn1 (no affine); splice(0,2,4)
    fold_mfma<<<512, 256, 0, stream>>>(h2_w, h2_b, st1, nullptr, nullptr,
                                       Wh2, bf2, 512, 512, 512, 3, 1536, 1536,
                                       1.f / (B * T1));
    conv_mfma<1, 512, 1536><<<dim3(16, 4, B), 256, 0, stream>>>(
        bufA, Wh2, bf2, bufB, st2, 512, T2, 2);

    // L3: fold bn2; splice(0,3,6)
    fold_mfma<<<512, 256, 0, stream>>>(h3_w, h3_b, st2, bn2_g, bn2_b,
                                       Wh3, bf3, 512, 512, 512, 3, 1536, 1536,
                                       1.f / (B * T2));
    conv_mfma<1, 512, 1536><<<dim3(16, 4, B), 256, 0, stream>>>(
        bufB, Wh3, bf3, bufA, st3, 512, T3, 3);

    // L4: fold bn3; conv 512x512, relu6
    fold_mfma<<<512, 256, 0, stream>>>(h4_w, h4_b, st3, bn3_g, bn3_b,
                                       Wh4, bf4, 512, 512, 512, 1, 512, 512,
                                       1.f / (B * T3));
    conv_mfma<2, 512, 512><<<dim3(16, 4, B), 256, 0, stream>>>(
        bufA, Wh4, bf4, bufB, st4, 512, T3, 0);

    // L5: fold bn4; conv 1500(pad 1536)x512 + relu6 + fused t-chunk reduction
    fold_mfma<<<1536, 256, 0, stream>>>(h5_w, h5_b, st4, bn4_g, bn4_b,
                                        Wh5, bf5, 1500, 512, 512, 1, 512, 512,
                                        1.f / (B * T3));
    pool_mfma<512><<<3072, 256, 0, stream>>>(bufB, Wh5, bf5, Sp, Qp, T3, 1536);

    // bn5 + stats pooling -> stat [B,3000]
    pool_finalize<<<6, 256, 0, stream>>>(Sp, Qp, bn5_g, bn5_b, stat, 1536, 1500, T3);

    // FC head (fused FC + batch-BN, one block per output channel)
    fc_bn<<<512, 256, 0, stream>>>(stat, l1_w, l1_b, bn6_g, bn6_b, f1, 3000, 512);
    fc_bn<<<512, 256, 0, stream>>>(f1, l2_w, l2_b, bn7_g, bn7_b, (float*)d_out, 512, 512);
}

// Round 14
// 689.589 us; speedup vs baseline: 1.1188x; 1.1188x over previous
//
#include <hip/hip_runtime.h>
#include <cstdint>

#define EPSF 1e-5f

namespace {

typedef _Float16 f16;
typedef _Float16 v8h __attribute__((ext_vector_type(8)));
typedef float v4f __attribute__((ext_vector_type(4)));

constexpr int B  = 32;
constexpr int T0 = 2048, F0 = 20;
constexpr int T1 = 2044, T2 = 2040, T3 = 2034;
constexpr int TS = 2048;   // uniform stored t-rows per (b, channel-octet)

// async global->LDS DMA, 16B per lane; LDS dest = wave-uniform base + lane*16
__device__ __forceinline__ void gload16(const void* g, void* l) {
    typedef const __attribute__((address_space(1))) void* gp_t;
    typedef __attribute__((address_space(3))) void* lp_t;
    __builtin_amdgcn_global_load_lds((gp_t)(unsigned long long)g,
                                     (lp_t)(unsigned int)(unsigned long long)l,
                                     16, 0, 0);
}
__device__ __forceinline__ void wait_vm4() { asm volatile("s_waitcnt vmcnt(4)" ::: "memory"); }
__device__ __forceinline__ void wait_vm0() { asm volatile("s_waitcnt vmcnt(0)" ::: "memory"); }

// x [B, T0, F0] fp32 -> xT [b][3 oct][TS][8] fp16; first blocks also zero st[4096]
__global__ __launch_bounds__(256) void transpose_x(const float* __restrict__ x,
                                                   f16* __restrict__ xT,
                                                   float* __restrict__ stZ)
{
    int idx = blockIdx.x * 256 + threadIdx.x;
    if (idx < 4096) stZ[idx] = 0.f;            // zero st1..st4 (atomic stats targets)
    constexpr int total = B * 3 * TS * 8;
    if (idx >= total) return;
    int fl = idx & 7;
    int t  = (idx >> 3) & (TS - 1);
    int fo = (idx >> 14) % 3;
    int b  = idx / (3 << 14);
    int f  = fo * 8 + fl;
    float v = (f < F0) ? x[((size_t)b * T0 + t) * F0 + f] : 0.f;
    xT[idx] = (f16)v;
}

// Fold prev-layer BN into weights, cast fp16, reorder K c-major (k = c*FP + f),
// write SWIZZLED slab order [o/128][k/8][o%128][8]. FP,C compile-time -> no v_rcp divs.
template<int FP, int C>
__global__ __launch_bounds__(256) void fold_mfma(
    const float* __restrict__ W, const float* __restrict__ bias,
    const float* __restrict__ st, const float* __restrict__ gamma, const float* __restrict__ beta,
    f16* __restrict__ Wh, float* __restrict__ bf,
    int Oreal, int Freal, int Cin, int CinOrig, float invN)
{
    int o = blockIdx.x;
    auto sidx = [&](int k) {
        return ((size_t)((o >> 7) * (Cin >> 3) + (k >> 3)) * 128 + (o & 127)) * 8 + (k & 7);
    };
    if (o >= Oreal) {
        for (int k = threadIdx.x; k < Cin; k += 256) Wh[sidx(k)] = (f16)0.f;
        if (threadIdx.x == 0) bf[o] = 0.f;
        return;
    }
    float local = 0.f;
    for (int k = threadIdx.x; k < Cin; k += 256) {
        int c = k / FP, f = k - c * FP;        // FP constexpr -> magic-mul/shift
        float wv = 0.f;
        if (c < C && f < Freal) {
            float sc = 1.f, sh = 0.f;
            if (st) {
                float mean = st[f] * invN;
                float var  = st[Freal + f] * invN - mean * mean;
                sc = rsqrtf(var + EPSF);
                if (gamma) sc *= gamma[f];
                sh = (beta ? beta[f] : 0.f) - mean * sc;
            }
            float w = W[(size_t)o * CinOrig + f * C + c];
            wv = w * sc;
            local += w * sh;
        }
        Wh[sidx(k)] = (f16)wv;
    }
#pragma unroll
    for (int d = 32; d; d >>= 1) local += __shfl_down(local, d);
    __shared__ float red[4];
    if ((threadIdx.x & 63) == 0) red[threadIdx.x >> 6] = local;
    __syncthreads();
    if (threadIdx.x == 0) bf[o] = bias[o] + red[0] + red[1] + red[2] + red[3];
}

// Fused splice+conv via MFMA; 1KB-coalesced DMA staging, dbuf pipeline (vmcnt(4)).
// Per-channel stats accumulated via device-scope atomics into st[o], st[512+o].
template<int ACT, int FPR, int CIN>
__global__ __launch_bounds__(256, 4) void conv_mfma(
    const f16* __restrict__ inT, const f16* __restrict__ Wh,
    const float* __restrict__ bias, f16* __restrict__ outT,
    float* __restrict__ st, int O, int Tout, int offMul)
{
    __shared__ __align__(16) f16 Ilds[2][4 * 128 * 8];
    __shared__ __align__(16) f16 Wlds[2][4 * 128 * 8];
    __shared__ float redS[2][128];
    __shared__ float redQ[2][128];
    const int tid  = threadIdx.x;
    const int lane = tid & 63, wave = tid >> 6;
    const int wt = wave & 1, wo = wave >> 1;
    const int quad = lane >> 4, l16 = lane & 15;
    const int tB = blockIdx.x * 128, oB = blockIdx.y * 128, b = blockIdx.z;
    const f16* inb = inT + (size_t)b * FPR * TS;          // [c_oct][TS][8]
    const size_t wBase = (size_t)(oB >> 7) * (CIN >> 3);

    auto stage = [&](int iB, int pb) {
#pragma unroll
        for (int j = 0; j < 4; ++j) {
            int s = wave * 4 + j;
            int koct = (s & 7) >> 1, half = s & 1;
            if (s < 8) {
                int kidx = iB + koct * 8;
                int c = kidx / FPR, f = kidx - c * FPR;
                int t = tB + half * 64 + lane + c * offMul;
                gload16(inb + ((size_t)(f >> 3) * TS + t) * 8,
                        &Ilds[pb][(koct * 128 + half * 64) * 8]);
            } else {
                gload16(Wh + ((wBase + (iB >> 3) + koct) * 128 + half * 64 + lane) * 8,
                        &Wlds[pb][(koct * 128 + half * 64) * 8]);
            }
        }
    };

    v4f acc[4][4];
#pragma unroll
    for (int mi = 0; mi < 4; ++mi)
#pragma unroll
        for (int ni = 0; ni < 4; ++ni)
#pragma unroll
            for (int r = 0; r < 4; ++r) acc[mi][ni][r] = 0.f;

    constexpr int nIter = CIN >> 5;
    stage(0, 0);
#pragma unroll 2
    for (int k = 0; k < nIter; ++k) {
        const int pb = k & 1;
        __syncthreads();                        // readers of pb^1 done
        if (k + 1 < nIter) { stage((k + 1) * 32, pb ^ 1); wait_vm4(); }
        else               { wait_vm0(); }
        __syncthreads();                        // stage(k) complete everywhere
        v8h afr[4], bfr[4];
#pragma unroll
        for (int mi = 0; mi < 4; ++mi)
            afr[mi] = *(const v8h*)&Ilds[pb][(quad * 128 + wt * 64 + mi * 16 + l16) * 8];
#pragma unroll
        for (int ni = 0; ni < 4; ++ni)
            bfr[ni] = *(const v8h*)&Wlds[pb][(quad * 128 + wo * 64 + ni * 16 + l16) * 8];
#pragma unroll
        for (int mi = 0; mi < 4; ++mi)
#pragma unroll
            for (int ni = 0; ni < 4; ++ni)
                acc[mi][ni] = __builtin_amdgcn_mfma_f32_16x16x32_f16(
                    afr[mi], bfr[ni], acc[mi][ni], 0, 0, 0);
    }

    float Sl[4] = {0, 0, 0, 0}, Ql[4] = {0, 0, 0, 0};
#pragma unroll
    for (int ni = 0; ni < 4; ++ni) {
        const int o  = oB + wo * 64 + ni * 16 + l16;
        const float bs = bias[o];
        f16* orow = outT + (size_t)b * O * TS + (size_t)(o >> 3) * TS * 8 + (o & 7);
#pragma unroll
        for (int mi = 0; mi < 4; ++mi)
#pragma unroll
            for (int r = 0; r < 4; ++r) {
                int t = tB + wt * 64 + mi * 16 + quad * 4 + r;
                if (t < Tout) {
                    float v = acc[mi][ni][r] + bs;
                    v = fmaxf(v, 0.f);
                    if (ACT == 2) v = fminf(v, 6.f);
                    orow[(size_t)t * 8] = (f16)v;
                    Sl[ni] += v; Ql[ni] += v * v;
                }
            }
    }
#pragma unroll
    for (int ni = 0; ni < 4; ++ni) {
        float s = Sl[ni], q = Ql[ni];
        s += __shfl_down(s, 32); q += __shfl_down(q, 32);
        s += __shfl_down(s, 16); q += __shfl_down(q, 16);
        if (lane < 16) {
            redS[wt][wo * 64 + ni * 16 + lane] = s;
            redQ[wt][wo * 64 + ni * 16 + lane] = q;
        }
    }
    __syncthreads();
    if (tid < 128) {
        atomicAdd(&st[oB + tid],       redS[0][tid] + redS[1][tid]);
        atomicAdd(&st[512 + oB + tid], redQ[0][tid] + redQ[1][tid]);
    }
}

// L5: MFMA conv 1536x512 + relu6 + per-(b,o) sum/sumsq over a 512-t chunk.
// XCD-locality swizzle (R11/R12 proven). CIN=512: kPer=16, nChunk=4, total=64.
template<int CIN>
__global__ __launch_bounds__(256, 4) void pool_mfma(
    const f16* __restrict__ inT, const f16* __restrict__ Wh,
    const float* __restrict__ bias, float* __restrict__ Sp, float* __restrict__ Qp,
    int T, int Opad)
{
    const int L    = blockIdx.x;
    const int slot = L >> 3;
    const int oB   = (slot % 12) * 128;
    const int cz   = (L & 7) + 8 * (slot / 12);   // 0..127
    const int b    = cz & 31, z = cz >> 5;

    __shared__ __align__(16) f16 Ilds[2][4 * 128 * 8];
    __shared__ __align__(16) f16 Wlds[2][4 * 128 * 8];
    __shared__ float redS[2][128];
    __shared__ float redQ[2][128];
    const int tid  = threadIdx.x;
    const int lane = tid & 63, wave = tid >> 6;
    const int wt = wave & 1, wo = wave >> 1;
    const int quad = lane >> 4, l16 = lane & 15;
    const f16* inb = inT + (size_t)b * CIN * TS;
    const size_t wBase = (size_t)(oB >> 7) * (CIN >> 3);

    auto stage = [&](int t0, int iB, int pb) {
#pragma unroll
        for (int j = 0; j < 4; ++j) {
            int s = wave * 4 + j;
            int koct = (s & 7) >> 1, half = s & 1;
            if (s < 8) {
                gload16(inb + ((size_t)((iB >> 3) + koct) * TS + t0 + half * 64 + lane) * 8,
                        &Ilds[pb][(koct * 128 + half * 64) * 8]);
            } else {
                gload16(Wh + ((wBase + (iB >> 3) + koct) * 128 + half * 64 + lane) * 8,
                        &Wlds[pb][(koct * 128 + half * 64) * 8]);
            }
        }
    };

    float Sl[4] = {0, 0, 0, 0}, Ql[4] = {0, 0, 0, 0};
    float bs[4];
#pragma unroll
    for (int ni = 0; ni < 4; ++ni) bs[ni] = bias[oB + wo * 64 + ni * 16 + l16];

    const int tBase = z * 512;
    constexpr int kPer  = CIN >> 5;             // 16
    constexpr int total = 4 * kPer;             // 4 chunks of 128 t per block

    v4f acc[4][4];
#pragma unroll
    for (int mi = 0; mi < 4; ++mi)
#pragma unroll
        for (int ni = 0; ni < 4; ++ni)
#pragma unroll
            for (int r = 0; r < 4; ++r) acc[mi][ni][r] = 0.f;

    stage(tBase, 0, 0);
#pragma unroll 2
    for (int it = 0; it < total; ++it) {
        const int pb = it & 1;
        __syncthreads();
        if (it + 1 < total) {
            int nx = it + 1;
            stage(tBase + (nx >> 4) * 128, (nx & (kPer - 1)) * 32, pb ^ 1);
            wait_vm4();
        } else {
            wait_vm0();
        }
        __syncthreads();
        v8h afr[4], bfr[4];
#pragma unroll
        for (int mi = 0; mi < 4; ++mi)
            afr[mi] = *(const v8h*)&Ilds[pb][(quad * 128 + wt * 64 + mi * 16 + l16) * 8];
#pragma unroll
        for (int ni = 0; ni < 4; ++ni)
            bfr[ni] = *(const v8h*)&Wlds[pb][(quad * 128 + wo * 64 + ni * 16 + l16) * 8];
#pragma unroll
        for (int mi = 0; mi < 4; ++mi)
#pragma unroll
            for (int ni = 0; ni < 4; ++ni)
                acc[mi][ni] = __builtin_amdgcn_mfma_f32_16x16x32_f16(
                    afr[mi], bfr[ni], acc[mi][ni], 0, 0, 0);

        if ((it & (kPer - 1)) == kPer - 1) {    // chunk done: flush acc -> Sl/Ql
            int tB = tBase + (it >> 4) * 128;
#pragma unroll
            for (int ni = 0; ni < 4; ++ni)
#pragma unroll
                for (int mi = 0; mi < 4; ++mi)
#pragma unroll
                    for (int r = 0; r < 4; ++r) {
                        int t = tB + wt * 64 + mi * 16 + quad * 4 + r;
                        if (t < T) {
                            float v = fminf(fmaxf(acc[mi][ni][r] + bs[ni], 0.f), 6.f);
                            Sl[ni] += v; Ql[ni] += v * v;
                        }
                        acc[mi][ni][r] = 0.f;
                    }
        }
    }

#pragma unroll
    for (int ni = 0; ni < 4; ++ni) {
        float s = Sl[ni], q = Ql[ni];
        s += __shfl_down(s, 32); q += __shfl_down(q, 32);
        s += __shfl_down(s, 16); q += __shfl_down(q, 16);
        if (lane < 16) {
            redS[wt][wo * 64 + ni * 16 + lane] = s;
            redQ[wt][wo * 64 + ni * 16 + lane] = q;
        }
    }
    __syncthreads();
    if (tid < 128) {
        int o = oB + tid;
        Sp[((size_t)z * B + b) * Opad + o] = redS[0][tid] + redS[1][tid];
        Qp[((size_t)z * B + b) * Opad + o] = redQ[0][tid] + redQ[1][tid];
    }
}

// bn5 (global over B,T) + per-(b,c) mean/std(ddof=1) -> stat [B, 2*Oreal]
__global__ __launch_bounds__(256) void pool_finalize(
    const float* __restrict__ Sp, const float* __restrict__ Qp,
    const float* __restrict__ g5, const float* __restrict__ b5,
    float* __restrict__ stat, int Opad, int Oreal, int T)
{
    int co = blockIdx.x * 256 + threadIdx.x;
    if (co >= Oreal) return;
    double sS = 0, sQ = 0;
    for (int z = 0; z < 4; ++z)
        for (int b = 0; b < B; ++b) {
            sS += Sp[((size_t)z * B + b) * Opad + co];
            sQ += Qp[((size_t)z * B + b) * Opad + co];
        }
    double invN = 1.0 / ((double)B * T);
    double m = sS * invN;
    double v = sQ * invN - m * m;
    float sc = g5[co] * rsqrtf((float)v + EPSF);
    float sh = b5[co] - (float)m * sc;
    for (int b = 0; b < B; ++b) {
        double sb = 0, qb = 0;
        for (int z = 0; z < 4; ++z) {
            sb += Sp[((size_t)z * B + b) * Opad + co];
            qb += Qp[((size_t)z * B + b) * Opad + co];
        }
        double mb = sb / T;
        double vb = (qb - sb * sb / T) / (T - 1);
        if (vb < 0) vb = 0;
        stat[(size_t)b * 2 * Oreal + co]         = (float)mb * sc + sh;
        stat[(size_t)b * 2 * Oreal + Oreal + co] = sqrtf((float)vb) * fabsf(sc);
    }
}

// wave-per-output FC: y[b,o] = relu6( dot(x[b,:], W[o,:]) + bias[o] )
__global__ __launch_bounds__(256) void fc_relu6(const float* __restrict__ x,
                                                const float* __restrict__ W,
                                                const float* __restrict__ bias,
                                                float* __restrict__ y, int Cin, int O)
{
    int wid = (blockIdx.x * 256 + threadIdx.x) >> 6;
    int lane = threadIdx.x & 63;
    if (wid >= B * O) return;
    int b = wid / O, o = wid - b * O;
    const float* xr = x + (size_t)b * Cin;
    const float* wr = W + (size_t)o * Cin;
    float s = 0.f;
    for (int c = lane; c < Cin; c += 64) s = fmaf(xr[c], wr[c], s);
#pragma unroll
    for (int d = 32; d; d >>= 1) s += __shfl_down(s, d);
    if (lane == 0) y[wid] = fminf(fmaxf(s + bias[o], 0.f), 6.f);
}

// BatchNorm over batch dim on [B, O]
__global__ __launch_bounds__(512) void bn_batch(const float* __restrict__ x,
                                                const float* __restrict__ g,
                                                const float* __restrict__ be,
                                                float* __restrict__ y, int O)
{
    int o = threadIdx.x;
    if (o >= O) return;
    float s = 0.f, q = 0.f;
    for (int b = 0; b < B; ++b) { float v = x[b * O + o]; s += v; q += v * v; }
    float m = s / B;
    float var = q / B - m * m;
    float sc = g[o] * rsqrtf(var + EPSF);
    float sh = be[o] - m * sc;
    for (int b = 0; b < B; ++b) y[b * O + o] = x[b * O + o] * sc + sh;
}

} // anonymous namespace

extern "C" void kernel_launch(void* const* d_in, const int* in_sizes, int n_in,
                              void* d_out, int out_size, void* d_ws, size_t ws_size,
                              hipStream_t stream)
{
    (void)in_sizes; (void)n_in; (void)out_size; (void)ws_size;
    const float* x     = (const float*)d_in[0];
    const float* h1_w  = (const float*)d_in[1];
    const float* h1_b  = (const float*)d_in[2];
    const float* h2_w  = (const float*)d_in[3];
    const float* h2_b  = (const float*)d_in[4];
    const float* bn2_g = (const float*)d_in[5];
    const float* bn2_b = (const float*)d_in[6];
    const float* h3_w  = (const float*)d_in[7];
    const float* h3_b  = (const float*)d_in[8];
    const float* bn3_g = (const float*)d_in[9];
    const float* bn3_b = (const float*)d_in[10];
    const float* h4_w  = (const float*)d_in[11];
    const float* h4_b  = (const float*)d_in[12];
    const float* bn4_g = (const float*)d_in[13];
    const float* bn4_b = (const float*)d_in[14];
    const float* h5_w  = (const float*)d_in[15];
    const float* h5_b  = (const float*)d_in[16];
    const float* bn5_g = (const float*)d_in[17];
    const float* bn5_b = (const float*)d_in[18];
    const float* l1_w  = (const float*)d_in[19];
    const float* l1_b  = (const float*)d_in[20];
    const float* bn6_g = (const float*)d_in[21];
    const float* bn6_b = (const float*)d_in[22];
    const float* l2_w  = (const float*)d_in[23];
    const float* l2_b  = (const float*)d_in[24];
    const float* bn7_g = (const float*)d_in[25];
    const float* bn7_b = (const float*)d_in[26];

    char* ws = (char*)d_ws;
    size_t off = 0;
    auto alloc = [&](size_t bytes) {
        char* p = ws + off;
        off += (bytes + 255) & ~(size_t)255;
        return (void*)p;
    };
    f16* xT    = (f16*)alloc(((size_t)B * 3  * TS * 8 + 2048) * 2);
    f16* bufA  = (f16*)alloc(((size_t)B * 64 * TS * 8 + 2048) * 2);  // o1, later o3
    f16* bufB  = (f16*)alloc(((size_t)B * 64 * TS * 8 + 2048) * 2);  // o2, later o4
    f16* Wh1   = (f16*)alloc((size_t)512 * 128 * 2);
    f16* Wh2   = (f16*)alloc((size_t)512 * 1536 * 2);
    f16* Wh3   = (f16*)alloc((size_t)512 * 1536 * 2);
    f16* Wh4   = (f16*)alloc((size_t)512 * 512 * 2);
    f16* Wh5   = (f16*)alloc((size_t)1536 * 512 * 2);
    float* bf1 = (float*)alloc(512 * 4);
    float* bf2 = (float*)alloc(512 * 4);
    float* bf3 = (float*)alloc(512 * 4);
    float* bf4 = (float*)alloc(512 * 4);
    float* bf5 = (float*)alloc(1536 * 4);
    float* stZ = (float*)alloc(4096 * 4);       // st1..st4, zeroed by transpose_x
    float* st1 = stZ, *st2 = stZ + 1024, *st3 = stZ + 2048, *st4 = stZ + 3072;
    float* Sp  = (float*)alloc((size_t)4 * B * 1536 * 4);
    float* Qp  = (float*)alloc((size_t)4 * B * 1536 * 4);
    float* stat = (float*)alloc((size_t)B * 3000 * 4);
    float* f1  = (float*)alloc((size_t)B * 512 * 4);
    float* f2  = (float*)alloc((size_t)B * 512 * 4);

    transpose_x<<<(B * 3 * TS * 8 + 255) / 256, 256, 0, stream>>>(x, xT, stZ);

    // L1: reorder/cast/swizzle W1 (no prev BN); splice(0..4), Cin pad->128
    fold_mfma<24, 5><<<512, 256, 0, stream>>>(h1_w, h1_b, nullptr, nullptr, nullptr,
                                              Wh1, bf1, 512, 20, 128, 100, 0.f);
    conv_mfma<1, 24, 128><<<dim3(16, 4, B), 256, 0, stream>>>(
        xT, Wh1, bf1, bufA, st1, 512, T1, 1);

    // L2: fold bn1 (no affine); splice(0,2,4)
    fold_mfma<512, 3><<<512, 256, 0, stream>>>(h2_w, h2_b, st1, nullptr, nullptr,
                                               Wh2, bf2, 512, 512, 1536, 1536,
                                               1.f / (B * T1));
    conv_mfma<1, 512, 1536><<<dim3(16, 4, B), 256, 0, stream>>>(
        bufA, Wh2, bf2, bufB, st2, 512, T2, 2);

    // L3: fold bn2; splice(0,3,6)
    fold_mfma<512, 3><<<512, 256, 0, stream>>>(h3_w, h3_b, st2, bn2_g, bn2_b,
                                               Wh3, bf3, 512, 512, 1536, 1536,
                                               1.f / (B * T2));
    conv_mfma<1, 512, 1536><<<dim3(16, 4, B), 256, 0, stream>>>(
        bufB, Wh3, bf3, bufA, st3, 512, T3, 3);

    // L4: fold bn3; conv 512x512, relu6
    fold_mfma<512, 1><<<512, 256, 0, stream>>>(h4_w, h4_b, st3, bn3_g, bn3_b,
                                               Wh4, bf4, 512, 512, 512, 512,
                                               1.f / (B * T3));
    conv_mfma<2, 512, 512><<<dim3(16, 4, B), 256, 0, stream>>>(
        bufA, Wh4, bf4, bufB, st4, 512, T3, 0);

    // L5: fold bn4; conv 1500(pad 1536)x512 + relu6 + fused t-chunk reduction
    fold_mfma<512, 1><<<1536, 256, 0, stream>>>(h5_w, h5_b, st4, bn4_g, bn4_b,
                                                Wh5, bf5, 1500, 512, 512, 512,
                                                1.f / (B * T3));
    pool_mfma<512><<<1536, 256, 0, stream>>>(bufB, Wh5, bf5, Sp, Qp, T3, 1536);

    // bn5 + stats pooling -> stat [B,3000]
    pool_finalize<<<6, 256, 0, stream>>>(Sp, Qp, bn5_g, bn5_b, stat, 1536, 1500, T3);

    // FC head
    fc_relu6<<<(B * 512 * 64 + 255) / 256, 256, 0, stream>>>(stat, l1_w, l1_b, f1, 3000, 512);
    bn_batch<<<1, 512, 0, stream>>>(f1, bn6_g, bn6_b, f1, 512);
    fc_relu6<<<(B * 512 * 64 + 255) / 256, 256, 0, stream>>>(f1, l2_w, l2_b, f2, 512, 512);
    bn_batch<<<1, 512, 0, stream>>>(f2, bn7_g, bn7_b, (float*)d_out, 512);
}

// Round 15
// 660.315 us; speedup vs baseline: 1.1684x; 1.0443x over previous
//
#include <hip/hip_runtime.h>
#include <cstdint>

#define EPSF 1e-5f

namespace {

typedef _Float16 f16;
typedef _Float16 v8h __attribute__((ext_vector_type(8)));
typedef float v4f __attribute__((ext_vector_type(4)));

constexpr int B  = 32;
constexpr int T0 = 2048, F0 = 20;
constexpr int T1 = 2044, T2 = 2040, T3 = 2034;
constexpr int TS = 2048;   // uniform stored t-rows per (b, channel-octet)

// async global->LDS DMA, 16B per lane; LDS dest = wave-uniform base + lane*16
__device__ __forceinline__ void gload16(const void* g, void* l) {
    typedef const __attribute__((address_space(1))) void* gp_t;
    typedef __attribute__((address_space(3))) void* lp_t;
    __builtin_amdgcn_global_load_lds((gp_t)(unsigned long long)g,
                                     (lp_t)(unsigned int)(unsigned long long)l,
                                     16, 0, 0);
}
__device__ __forceinline__ void wait_vm4() { asm volatile("s_waitcnt vmcnt(4)" ::: "memory"); }
__device__ __forceinline__ void wait_vm0() { asm volatile("s_waitcnt vmcnt(0)" ::: "memory"); }

// x [B, T0, F0] fp32 -> xT [b][3 oct][TS][8] fp16; first blocks also zero st[4096]
__global__ __launch_bounds__(256) void transpose_x(const float* __restrict__ x,
                                                   f16* __restrict__ xT,
                                                   float* __restrict__ stZ)
{
    int idx = blockIdx.x * 256 + threadIdx.x;
    if (idx < 4096) stZ[idx] = 0.f;            // zero st1..st4 (atomic stats targets)
    constexpr int total = B * 3 * TS * 8;
    if (idx >= total) return;
    int fl = idx & 7;
    int t  = (idx >> 3) & (TS - 1);
    int fo = (idx >> 14) % 3;
    int b  = idx / (3 << 14);
    int f  = fo * 8 + fl;
    float v = (f < F0) ? x[((size_t)b * T0 + t) * F0 + f] : 0.f;
    xT[idx] = (f16)v;
}

// Fold prev-layer BN into weights, cast fp16, reorder K c-major (k = c*FP + f),
// write SWIZZLED slab order [o/128][k/8][o%128][8]. FP,C compile-time -> no v_rcp divs.
template<int FP, int C>
__global__ __launch_bounds__(256) void fold_mfma(
    const float* __restrict__ W, const float* __restrict__ bias,
    const float* __restrict__ st, const float* __restrict__ gamma, const float* __restrict__ beta,
    f16* __restrict__ Wh, float* __restrict__ bf,
    int Oreal, int Freal, int Cin, int CinOrig, float invN)
{
    int o = blockIdx.x;
    auto sidx = [&](int k) {
        return ((size_t)((o >> 7) * (Cin >> 3) + (k >> 3)) * 128 + (o & 127)) * 8 + (k & 7);
    };
    if (o >= Oreal) {
        for (int k = threadIdx.x; k < Cin; k += 256) Wh[sidx(k)] = (f16)0.f;
        if (threadIdx.x == 0) bf[o] = 0.f;
        return;
    }
    float local = 0.f;
    for (int k = threadIdx.x; k < Cin; k += 256) {
        int c = k / FP, f = k - c * FP;        // FP constexpr -> magic-mul/shift
        float wv = 0.f;
        if (c < C && f < Freal) {
            float sc = 1.f, sh = 0.f;
            if (st) {
                float mean = st[f] * invN;
                float var  = st[Freal + f] * invN - mean * mean;
                sc = rsqrtf(var + EPSF);
                if (gamma) sc *= gamma[f];
                sh = (beta ? beta[f] : 0.f) - mean * sc;
            }
            float w = W[(size_t)o * CinOrig + f * C + c];
            wv = w * sc;
            local += w * sh;
        }
        Wh[sidx(k)] = (f16)wv;
    }
#pragma unroll
    for (int d = 32; d; d >>= 1) local += __shfl_down(local, d);
    __shared__ float red[4];
    if ((threadIdx.x & 63) == 0) red[threadIdx.x >> 6] = local;
    __syncthreads();
    if (threadIdx.x == 0) bf[o] = bias[o] + red[0] + red[1] + red[2] + red[3];
}

// Fused splice+conv via MFMA; 1KB-coalesced DMA staging, dbuf pipeline (vmcnt(4)).
// FPR==512 fast path: staging addresses carried as per-wave pointers advanced by
// uniform strides (splice-c wrap folded into the stride select) -> ~4 VALU/iter.
// Per-channel stats accumulated via device-scope atomics into st[o], st[512+o].
template<int ACT, int FPR, int CIN>
__global__ __launch_bounds__(256, 4) void conv_mfma(
    const f16* __restrict__ inT, const f16* __restrict__ Wh,
    const float* __restrict__ bias, f16* __restrict__ outT,
    float* __restrict__ st, int O, int Tout, int offMul)
{
    __shared__ __align__(16) f16 Ilds[2][4 * 128 * 8];
    __shared__ __align__(16) f16 Wlds[2][4 * 128 * 8];
    __shared__ float redS[2][128];
    __shared__ float redQ[2][128];
    const int tid  = threadIdx.x;
    const int lane = tid & 63, wave = tid >> 6;
    const int wt = wave & 1, wo = wave >> 1;
    const int quad = lane >> 4, l16 = lane & 15;
    const int tB = blockIdx.x * 128, oB = blockIdx.y * 128, b = blockIdx.z;
    const f16* inb = inT + (size_t)b * FPR * TS;          // [c_oct][TS][8]
    const size_t wBase = (size_t)(oB >> 7) * (CIN >> 3);

    v4f acc[4][4];
#pragma unroll
    for (int mi = 0; mi < 4; ++mi)
#pragma unroll
        for (int ni = 0; ni < 4; ++ni)
#pragma unroll
            for (int r = 0; r < 4; ++r) acc[mi][ni][r] = 0.f;

    constexpr int nIter = CIN >> 5;

    auto compute = [&](int pb) {
        v8h afr[4], bfr[4];
#pragma unroll
        for (int mi = 0; mi < 4; ++mi)
            afr[mi] = *(const v8h*)&Ilds[pb][(quad * 128 + wt * 64 + mi * 16 + l16) * 8];
#pragma unroll
        for (int ni = 0; ni < 4; ++ni)
            bfr[ni] = *(const v8h*)&Wlds[pb][(quad * 128 + wo * 64 + ni * 16 + l16) * 8];
#pragma unroll
        for (int mi = 0; mi < 4; ++mi)
#pragma unroll
            for (int ni = 0; ni < 4; ++ni)
                acc[mi][ni] = __builtin_amdgcn_mfma_f32_16x16x32_f16(
                    afr[mi], bfr[ni], acc[mi][ni], 0, 0, 0);
    };

    if constexpr (FPR == 512) {
        // pointer-carried staging
        const char* gp0;
        const char* gp1;
        intptr_t dN, dWr;
        if (wave < 2) {
            gp0 = (const char*)(inb + ((size_t)(2 * wave) * TS + tB + lane) * 8);
            gp1 = gp0 + (size_t)TS * 16;
            dN  = (intptr_t)4 * TS * 16;
            dWr = ((intptr_t)(-60) * TS + offMul) * 16;
        } else {
            gp0 = (const char*)(Wh + ((wBase + 2 * (wave - 2)) * 128 + lane) * 8);
            gp1 = gp0;
            dN  = 8192;
            dWr = 8192;   // conv weights monotonic: same stride at c-boundaries
        }
        auto stage_fast = [&](int pb) {
            f16* Ib = &Ilds[pb][0];
            f16* Wb = &Wlds[pb][0];
            if (wave < 2) {
                int k0 = 2 * wave;
                gload16(gp0,        Ib + (k0 * 128) * 8);
                gload16(gp0 + 1024, Ib + (k0 * 128 + 64) * 8);
                gload16(gp1,        Ib + ((k0 + 1) * 128) * 8);
                gload16(gp1 + 1024, Ib + ((k0 + 1) * 128 + 64) * 8);
            } else {
                int k0 = 2 * (wave - 2);
                gload16(gp0,        Wb + (k0 * 128) * 8);
                gload16(gp0 + 1024, Wb + (k0 * 128 + 64) * 8);
                gload16(gp0 + 2048, Wb + ((k0 + 1) * 128) * 8);
                gload16(gp0 + 3072, Wb + ((k0 + 1) * 128 + 64) * 8);
            }
        };
        auto advance = [&](int kFrom) {        // transition kFrom -> kFrom+1
            intptr_t d = (((kFrom + 1) & 15) == 0) ? dWr : dN;
            gp0 += d;
            if (wave < 2) gp1 += d;
        };

        stage_fast(0);
        advance(0);
#pragma unroll 2
        for (int k = 0; k < nIter; ++k) {
            const int pb = k & 1;
            __syncthreads();                    // readers of pb^1 done
            if (k + 1 < nIter) { stage_fast(pb ^ 1); advance(k + 1); wait_vm4(); }
            else               { wait_vm0(); }
            __syncthreads();                    // stage(k) complete everywhere
            compute(pb);
        }
    } else {
        // generic path (L1 only: CIN=128, 4 iters)
        auto stage = [&](int iB, int pb) {
#pragma unroll
            for (int j = 0; j < 4; ++j) {
                int s = wave * 4 + j;
                int koct = (s & 7) >> 1, half = s & 1;
                if (s < 8) {
                    int kidx = iB + koct * 8;
                    int c = kidx / FPR, f = kidx - c * FPR;
                    int t = tB + half * 64 + lane + c * offMul;
                    gload16(inb + ((size_t)(f >> 3) * TS + t) * 8,
                            &Ilds[pb][(koct * 128 + half * 64) * 8]);
                } else {
                    gload16(Wh + ((wBase + (iB >> 3) + koct) * 128 + half * 64 + lane) * 8,
                            &Wlds[pb][(koct * 128 + half * 64) * 8]);
                }
            }
        };
        stage(0, 0);
#pragma unroll 2
        for (int k = 0; k < nIter; ++k) {
            const int pb = k & 1;
            __syncthreads();
            if (k + 1 < nIter) { stage((k + 1) * 32, pb ^ 1); wait_vm4(); }
            else               { wait_vm0(); }
            __syncthreads();
            compute(pb);
        }
    }

    float Sl[4] = {0, 0, 0, 0}, Ql[4] = {0, 0, 0, 0};
#pragma unroll
    for (int ni = 0; ni < 4; ++ni) {
        const int o  = oB + wo * 64 + ni * 16 + l16;
        const float bs = bias[o];
        f16* orow = outT + (size_t)b * O * TS + (size_t)(o >> 3) * TS * 8 + (o & 7);
#pragma unroll
        for (int mi = 0; mi < 4; ++mi)
#pragma unroll
            for (int r = 0; r < 4; ++r) {
                int t = tB + wt * 64 + mi * 16 + quad * 4 + r;
                if (t < Tout) {
                    float v = acc[mi][ni][r] + bs;
                    v = fmaxf(v, 0.f);
                    if (ACT == 2) v = fminf(v, 6.f);
                    orow[(size_t)t * 8] = (f16)v;
                    Sl[ni] += v; Ql[ni] += v * v;
                }
            }
    }
#pragma unroll
    for (int ni = 0; ni < 4; ++ni) {
        float s = Sl[ni], q = Ql[ni];
        s += __shfl_down(s, 32); q += __shfl_down(q, 32);
        s += __shfl_down(s, 16); q += __shfl_down(q, 16);
        if (lane < 16) {
            redS[wt][wo * 64 + ni * 16 + lane] = s;
            redQ[wt][wo * 64 + ni * 16 + lane] = q;
        }
    }
    __syncthreads();
    if (tid < 128) {
        atomicAdd(&st[oB + tid],       redS[0][tid] + redS[1][tid]);
        atomicAdd(&st[512 + oB + tid], redQ[0][tid] + redQ[1][tid]);
    }
}

// L5: MFMA conv 1536x512 + relu6 + per-(b,o) sum/sumsq over a 512-t chunk.
// XCD-locality swizzle (R11/R12 proven). CIN=512: kPer=16, total=64.
// Pointer-carried staging with chunk-boundary wrap strides.
template<int CIN>
__global__ __launch_bounds__(256, 4) void pool_mfma(
    const f16* __restrict__ inT, const f16* __restrict__ Wh,
    const float* __restrict__ bias, float* __restrict__ Sp, float* __restrict__ Qp,
    int T, int Opad)
{
    const int L    = blockIdx.x;
    const int slot = L >> 3;
    const int oB   = (slot % 12) * 128;
    const int cz   = (L & 7) + 8 * (slot / 12);   // 0..127
    const int b    = cz & 31, z = cz >> 5;

    __shared__ __align__(16) f16 Ilds[2][4 * 128 * 8];
    __shared__ __align__(16) f16 Wlds[2][4 * 128 * 8];
    __shared__ float redS[2][128];
    __shared__ float redQ[2][128];
    const int tid  = threadIdx.x;
    const int lane = tid & 63, wave = tid >> 6;
    const int wt = wave & 1, wo = wave >> 1;
    const int quad = lane >> 4, l16 = lane & 15;
    const f16* inb = inT + (size_t)b * CIN * TS;
    const size_t wBase = (size_t)(oB >> 7) * (CIN >> 3);

    float Sl[4] = {0, 0, 0, 0}, Ql[4] = {0, 0, 0, 0};
    float bs[4];
#pragma unroll
    for (int ni = 0; ni < 4; ++ni) bs[ni] = bias[oB + wo * 64 + ni * 16 + l16];

    const int tBase = z * 512;
    constexpr int kPer  = CIN >> 5;             // 16
    constexpr int total = 4 * kPer;             // 4 chunks of 128 t per block

    v4f acc[4][4];
#pragma unroll
    for (int mi = 0; mi < 4; ++mi)
#pragma unroll
        for (int ni = 0; ni < 4; ++ni)
#pragma unroll
            for (int r = 0; r < 4; ++r) acc[mi][ni][r] = 0.f;

    // pointer-carried staging
    const char* gp0;
    const char* gp1;
    intptr_t dN, dWr;
    if (wave < 2) {
        gp0 = (const char*)(inb + ((size_t)(2 * wave) * TS + tBase + lane) * 8);
        gp1 = gp0 + (size_t)TS * 16;
        dN  = (intptr_t)4 * TS * 16;
        dWr = ((intptr_t)(-60) * TS + 128) * 16;   // iB resets, t0 += 128
    } else {
        gp0 = (const char*)(Wh + ((wBase + 2 * (wave - 2)) * 128 + lane) * 8);
        gp1 = gp0;
        dN  = 8192;
        dWr = (intptr_t)(-60) * 128 * 16;          // iB resets, same chunk weights
    }
    auto stage_fast = [&](int pb) {
        f16* Ib = &Ilds[pb][0];
        f16* Wb = &Wlds[pb][0];
        if (wave < 2) {
            int k0 = 2 * wave;
            gload16(gp0,        Ib + (k0 * 128) * 8);
            gload16(gp0 + 1024, Ib + (k0 * 128 + 64) * 8);
            gload16(gp1,        Ib + ((k0 + 1) * 128) * 8);
            gload16(gp1 + 1024, Ib + ((k0 + 1) * 128 + 64) * 8);
        } else {
            int k0 = 2 * (wave - 2);
            gload16(gp0,        Wb + (k0 * 128) * 8);
            gload16(gp0 + 1024, Wb + (k0 * 128 + 64) * 8);
            gload16(gp0 + 2048, Wb + ((k0 + 1) * 128) * 8);
            gload16(gp0 + 3072, Wb + ((k0 + 1) * 128 + 64) * 8);
        }
    };
    auto advance = [&](int itFrom) {
        intptr_t d = (((itFrom + 1) & 15) == 0) ? dWr : dN;
        gp0 += d;
        if (wave < 2) gp1 += d;
    };

    stage_fast(0);
    advance(0);
#pragma unroll 2
    for (int it = 0; it < total; ++it) {
        const int pb = it & 1;
        __syncthreads();
        if (it + 1 < total) { stage_fast(pb ^ 1); advance(it + 1); wait_vm4(); }
        else                { wait_vm0(); }
        __syncthreads();
        v8h afr[4], bfr[4];
#pragma unroll
        for (int mi = 0; mi < 4; ++mi)
            afr[mi] = *(const v8h*)&Ilds[pb][(quad * 128 + wt * 64 + mi * 16 + l16) * 8];
#pragma unroll
        for (int ni = 0; ni < 4; ++ni)
            bfr[ni] = *(const v8h*)&Wlds[pb][(quad * 128 + wo * 64 + ni * 16 + l16) * 8];
#pragma unroll
        for (int mi = 0; mi < 4; ++mi)
#pragma unroll
            for (int ni = 0; ni < 4; ++ni)
                acc[mi][ni] = __builtin_amdgcn_mfma_f32_16x16x32_f16(
                    afr[mi], bfr[ni], acc[mi][ni], 0, 0, 0);

        if ((it & (kPer - 1)) == kPer - 1) {    // chunk done: flush acc -> Sl/Ql
            int tB = tBase + (it >> 4) * 128;
#pragma unroll
            for (int ni = 0; ni < 4; ++ni)
#pragma unroll
                for (int mi = 0; mi < 4; ++mi)
#pragma unroll
                    for (int r = 0; r < 4; ++r) {
                        int t = tB + wt * 64 + mi * 16 + quad * 4 + r;
                        if (t < T) {
                            float v = fminf(fmaxf(acc[mi][ni][r] + bs[ni], 0.f), 6.f);
                            Sl[ni] += v; Ql[ni] += v * v;
                        }
                        acc[mi][ni][r] = 0.f;
                    }
        }
    }

#pragma unroll
    for (int ni = 0; ni < 4; ++ni) {
        float s = Sl[ni], q = Ql[ni];
        s += __shfl_down(s, 32); q += __shfl_down(q, 32);
        s += __shfl_down(s, 16); q += __shfl_down(q, 16);
        if (lane < 16) {
            redS[wt][wo * 64 + ni * 16 + lane] = s;
            redQ[wt][wo * 64 + ni * 16 + lane] = q;
        }
    }
    __syncthreads();
    if (tid < 128) {
        int o = oB + tid;
        Sp[((size_t)z * B + b) * Opad + o] = redS[0][tid] + redS[1][tid];
        Qp[((size_t)z * B + b) * Opad + o] = redQ[0][tid] + redQ[1][tid];
    }
}

// bn5 (global over B,T) + per-(b,c) mean/std(ddof=1) -> stat [B, 2*Oreal]
__global__ __launch_bounds__(256) void pool_finalize(
    const float* __restrict__ Sp, const float* __restrict__ Qp,
    const float* __restrict__ g5, const float* __restrict__ b5,
    float* __restrict__ stat, int Opad, int Oreal, int T)
{
    int co = blockIdx.x * 256 + threadIdx.x;
    if (co >= Oreal) return;
    double sS = 0, sQ = 0;
    for (int z = 0; z < 4; ++z)
        for (int b = 0; b < B; ++b) {
            sS += Sp[((size_t)z * B + b) * Opad + co];
            sQ += Qp[((size_t)z * B + b) * Opad + co];
        }
    double invN = 1.0 / ((double)B * T);
    double m = sS * invN;
    double v = sQ * invN - m * m;
    float sc = g5[co] * rsqrtf((float)v + EPSF);
    float sh = b5[co] - (float)m * sc;
    for (int b = 0; b < B; ++b) {
        double sb = 0, qb = 0;
        for (int z = 0; z < 4; ++z) {
            sb += Sp[((size_t)z * B + b) * Opad + co];
            qb += Qp[((size_t)z * B + b) * Opad + co];
        }
        double mb = sb / T;
        double vb = (qb - sb * sb / T) / (T - 1);
        if (vb < 0) vb = 0;
        stat[(size_t)b * 2 * Oreal + co]         = (float)mb * sc + sh;
        stat[(size_t)b * 2 * Oreal + Oreal + co] = sqrtf((float)vb) * fabsf(sc);
    }
}

// wave-per-output FC: y[b,o] = relu6( dot(x[b,:], W[o,:]) + bias[o] )
__global__ __launch_bounds__(256) void fc_relu6(const float* __restrict__ x,
                                                const float* __restrict__ W,
                                                const float* __restrict__ bias,
                                                float* __restrict__ y, int Cin, int O)
{
    int wid = (blockIdx.x * 256 + threadIdx.x) >> 6;
    int lane = threadIdx.x & 63;
    if (wid >= B * O) return;
    int b = wid / O, o = wid - b * O;
    const float* xr = x + (size_t)b * Cin;
    const float* wr = W + (size_t)o * Cin;
    float s = 0.f;
    for (int c = lane; c < Cin; c += 64) s = fmaf(xr[c], wr[c], s);
#pragma unroll
    for (int d = 32; d; d >>= 1) s += __shfl_down(s, d);
    if (lane == 0) y[wid] = fminf(fmaxf(s + bias[o], 0.f), 6.f);
}

// BatchNorm over batch dim on [B, O]
__global__ __launch_bounds__(512) void bn_batch(const float* __restrict__ x,
                                                const float* __restrict__ g,
                                                const float* __restrict__ be,
                                                float* __restrict__ y, int O)
{
    int o = threadIdx.x;
    if (o >= O) return;
    float s = 0.f, q = 0.f;
    for (int b = 0; b < B; ++b) { float v = x[b * O + o]; s += v; q += v * v; }
    float m = s / B;
    float var = q / B - m * m;
    float sc = g[o] * rsqrtf(var + EPSF);
    float sh = be[o] - m * sc;
    for (int b = 0; b < B; ++b) y[b * O + o] = x[b * O + o] * sc + sh;
}

} // anonymous namespace

extern "C" void kernel_launch(void* const* d_in, const int* in_sizes, int n_in,
                              void* d_out, int out_size, void* d_ws, size_t ws_size,
                              hipStream_t stream)
{
    (void)in_sizes; (void)n_in; (void)out_size; (void)ws_size;
    const float* x     = (const float*)d_in[0];
    const float* h1_w  = (const float*)d_in[1];
    const float* h1_b  = (const float*)d_in[2];
    const float* h2_w  = (const float*)d_in[3];
    const float* h2_b  = (const float*)d_in[4];
    const float* bn2_g = (const float*)d_in[5];
    const float* bn2_b = (const float*)d_in[6];
    const float* h3_w  = (const float*)d_in[7];
    const float* h3_b  = (const float*)d_in[8];
    const float* bn3_g = (const float*)d_in[9];
    const float* bn3_b = (const float*)d_in[10];
    const float* h4_w  = (const float*)d_in[11];
    const float* h4_b  = (const float*)d_in[12];
    const float* bn4_g = (const float*)d_in[13];
    const float* bn4_b = (const float*)d_in[14];
    const float* h5_w  = (const float*)d_in[15];
    const float* h5_b  = (const float*)d_in[16];
    const float* bn5_g = (const float*)d_in[17];
    const float* bn5_b = (const float*)d_in[18];
    const float* l1_w  = (const float*)d_in[19];
    const float* l1_b  = (const float*)d_in[20];
    const float* bn6_g = (const float*)d_in[21];
    const float* bn6_b = (const float*)d_in[22];
    const float* l2_w  = (const float*)d_in[23];
    const float* l2_b  = (const float*)d_in[24];
    const float* bn7_g = (const float*)d_in[25];
    const float* bn7_b = (const float*)d_in[26];

    char* ws = (char*)d_ws;
    size_t off = 0;
    auto alloc = [&](size_t bytes) {
        char* p = ws + off;
        off += (bytes + 255) & ~(size_t)255;
        return (void*)p;
    };
    f16* xT    = (f16*)alloc(((size_t)B * 3  * TS * 8 + 2048) * 2);
    f16* bufA  = (f16*)alloc(((size_t)B * 64 * TS * 8 + 2048) * 2);  // o1, later o3
    f16* bufB  = (f16*)alloc(((size_t)B * 64 * TS * 8 + 2048) * 2);  // o2, later o4
    f16* Wh1   = (f16*)alloc((size_t)512 * 128 * 2);
    f16* Wh2   = (f16*)alloc((size_t)512 * 1536 * 2);
    f16* Wh3   = (f16*)alloc((size_t)512 * 1536 * 2);
    f16* Wh4   = (f16*)alloc((size_t)512 * 512 * 2);
    f16* Wh5   = (f16*)alloc((size_t)1536 * 512 * 2);
    float* bf1 = (float*)alloc(512 * 4);
    float* bf2 = (float*)alloc(512 * 4);
    float* bf3 = (float*)alloc(512 * 4);
    float* bf4 = (float*)alloc(512 * 4);
    float* bf5 = (float*)alloc(1536 * 4);
    float* stZ = (float*)alloc(4096 * 4);       // st1..st4, zeroed by transpose_x
    float* st1 = stZ, *st2 = stZ + 1024, *st3 = stZ + 2048, *st4 = stZ + 3072;
    float* Sp  = (float*)alloc((size_t)4 * B * 1536 * 4);
    float* Qp  = (float*)alloc((size_t)4 * B * 1536 * 4);
    float* stat = (float*)alloc((size_t)B * 3000 * 4);
    float* f1  = (float*)alloc((size_t)B * 512 * 4);
    float* f2  = (float*)alloc((size_t)B * 512 * 4);

    transpose_x<<<(B * 3 * TS * 8 + 255) / 256, 256, 0, stream>>>(x, xT, stZ);

    // L1: reorder/cast/swizzle W1 (no prev BN); splice(0..4), Cin pad->128
    fold_mfma<24, 5><<<512, 256, 0, stream>>>(h1_w, h1_b, nullptr, nullptr, nullptr,
                                              Wh1, bf1, 512, 20, 128, 100, 0.f);
    conv_mfma<1, 24, 128><<<dim3(16, 4, B), 256, 0, stream>>>(
        xT, Wh1, bf1, bufA, st1, 512, T1, 1);

    // L2: fold bn1 (no affine); splice(0,2,4)
    fold_mfma<512, 3><<<512, 256, 0, stream>>>(h2_w, h2_b, st1, nullptr, nullptr,
                                               Wh2, bf2, 512, 512, 1536, 1536,
                                               1.f / (B * T1));
    conv_mfma<1, 512, 1536><<<dim3(16, 4, B), 256, 0, stream>>>(
        bufA, Wh2, bf2, bufB, st2, 512, T2, 2);

    // L3: fold bn2; splice(0,3,6)
    fold_mfma<512, 3><<<512, 256, 0, stream>>>(h3_w, h3_b, st2, bn2_g, bn2_b,
                                               Wh3, bf3, 512, 512, 1536, 1536,
                                               1.f / (B * T2));
    conv_mfma<1, 512, 1536><<<dim3(16, 4, B), 256, 0, stream>>>(
        bufB, Wh3, bf3, bufA, st3, 512, T3, 3);

    // L4: fold bn3; conv 512x512, relu6
    fold_mfma<512, 1><<<512, 256, 0, stream>>>(h4_w, h4_b, st3, bn3_g, bn3_b,
                                               Wh4, bf4, 512, 512, 512, 512,
                                               1.f / (B * T3));
    conv_mfma<2, 512, 512><<<dim3(16, 4, B), 256, 0, stream>>>(
        bufA, Wh4, bf4, bufB, st4, 512, T3, 0);

    // L5: fold bn4; conv 1500(pad 1536)x512 + relu6 + fused t-chunk reduction
    fold_mfma<512, 1><<<1536, 256, 0, stream>>>(h5_w, h5_b, st4, bn4_g, bn4_b,
                                                Wh5, bf5, 1500, 512, 512, 512,
                                                1.f / (B * T3));
    pool_mfma<512><<<1536, 256, 0, stream>>>(bufB, Wh5, bf5, Sp, Qp, T3, 1536);

    // bn5 + stats pooling -> stat [B,3000]
    pool_finalize<<<6, 256, 0, stream>>>(Sp, Qp, bn5_g, bn5_b, stat, 1536, 1500, T3);

    // FC head
    fc_relu6<<<(B * 512 * 64 + 255) / 256, 256, 0, stream>>>(stat, l1_w, l1_b, f1, 3000, 512);
    bn_batch<<<1, 512, 0, stream>>>(f1, bn6_g, bn6_b, f1, 512);
    fc_relu6<<<(B * 512 * 64 + 255) / 256, 256, 0, stream>>>(f1, l2_w, l2_b, f2, 512, 512);
    bn_batch<<<1, 512, 0, stream>>>(f2, bn7_g, bn7_b, (float*)d_out, 512);
}